// Round 3
// baseline (354.641 us; speedup 1.0000x reference)
//
#include <hip/hip_runtime.h>

typedef float v2f __attribute__((ext_vector_type(2)));

namespace {
constexpr int W = 1024;
constexpr int H = 1024;
constexpr int NIMG = 32;
constexpr int SROWS = 32;            // output rows per block strip
constexpr int NSTRIP = H / SROWS;    // 32 -> grid 1024 = 4 blocks/CU
constexpr int BLOCK = 256;           // 256 threads * 4 cols = 1024 cols
constexpr int PAD = 8;               // zero-pad columns each side
constexpr int RB = PAD + W + PAD;    // 1040 columns per row buffer

constexpr float C1 = 0.0004f;        // (0.01*2)^2
constexpr float C2 = 0.0036f;        // (0.03*2)^2

// normalized gaussian, sigma=1.5, win=11
constexpr float GW[11] = {
    0.00102838f, 0.00759876f, 0.03600077f, 0.10936070f, 0.21300554f,
    0.26601172f,
    0.21300554f, 0.10936070f, 0.03600077f, 0.00759876f, 0.00102838f};
}  // namespace

// Load one row, produce per-column packed pairs (u,v) = (x+y, x-y).
// y is block-uniform -> uniform branch, no per-lane masking.
__device__ __forceinline__ void load_uv(const float4* __restrict__ p1,
                                        const float4* __restrict__ p2, int y,
                                        int tid, v2f uv[4]) {
  if ((unsigned)y < (unsigned)H) {
    const float4 a = p1[y * (W / 4) + tid];
    const float4 b = p2[y * (W / 4) + tid];
    uv[0] = (v2f){a.x + b.x, a.x - b.x};
    uv[1] = (v2f){a.y + b.y, a.y - b.y};
    uv[2] = (v2f){a.z + b.z, a.z - b.z};
    uv[3] = (v2f){a.w + b.w, a.w - b.w};
  } else {
#pragma unroll
    for (int c = 0; c < 4; ++c) uv[c] = (v2f){0.f, 0.f};
  }
}

// Sum of SSIM map values over the strip; atomicAdd into ws[0] (double).
// launch_bounds(256,4): VGPR cap 128 -> 4 blocks/CU with 33 KB LDS each.
__global__ __launch_bounds__(BLOCK, 4) void ssim_main(
    const float* __restrict__ img1, const float* __restrict__ img2,
    double* __restrict__ ws) {
  // parity double-buffered row buffers, (u,v)-interleaved pairs:
  // bufUV holds (blur_v(u), blur_v(v)); bufSQ holds (blur_v(u^2), blur_v(v^2))
  __shared__ __align__(16) v2f bufUV[2][RB];
  __shared__ __align__(16) v2f bufSQ[2][RB];
  __shared__ float red[BLOCK / 64];

  const int tid = threadIdx.x;
  const int bid = blockIdx.x;
  const int img = bid / NSTRIP;
  const int strip = bid % NSTRIP;
  const int ys = strip * SROWS;

  const float4* p1 =
      reinterpret_cast<const float4*>(img1) + (size_t)img * (W / 4) * H;
  const float4* p2 =
      reinterpret_cast<const float4*>(img2) + (size_t)img * (W / 4) * H;

  // zero the horizontal pad columns (covered by the first per-row barrier)
  if (tid < 16) {
    const int c = (tid < 8) ? tid : (PAD + W + tid - 8);
#pragma unroll
    for (int par = 0; par < 2; ++par) {
      bufUV[par][c] = (v2f){0.f, 0.f};
      bufSQ[par][c] = (v2f){0.f, 0.f};
    }
  }

  // shift ring: rows r-5..r+4 in ruv[0..9]; pf prefetches row r+5
  v2f ruv[11][4];
#pragma unroll
  for (int s = 0; s < 10; ++s) load_uv(p1, p2, ys - 5 + s, tid, ruv[s]);
  v2f pf[4];
  load_uv(p1, p2, ys + 5, tid, pf);

  float acc = 0.f;

  for (int ii = 0; ii < SROWS; ++ii) {
    // commit prefetched row r+5, start prefetch of row r+6
#pragma unroll
    for (int c = 0; c < 4; ++c) ruv[10][c] = pf[c];
    load_uv(p1, p2, ys + ii + 6, tid, pf);

    // vertical 11-tap blur: packed (u,v) and (u^2,v^2) accumulators
    v2f buv[4], bsq[4];
#pragma unroll
    for (int c = 0; c < 4; ++c) {
      buv[c] = (v2f){0.f, 0.f};
      bsq[c] = (v2f){0.f, 0.f};
    }
#pragma unroll
    for (int k = 0; k < 11; ++k) {
      const v2f gv = (v2f){GW[k], GW[k]};
#pragma unroll
      for (int c = 0; c < 4; ++c) {
        const v2f x = ruv[k][c];
        const v2f gx = gv * x;                          // pk_mul
        buv[c] += gx;                                   // pk_add
        bsq[c] = __builtin_elementwise_fma(gx, x, bsq[c]);  // pk_fma
      }
    }

    const int par = ii & 1;
    // store 4 cols of pairs: 2x b128 per buffer
    reinterpret_cast<float4*>(&bufUV[par][PAD])[tid * 2 + 0] =
        make_float4(buv[0].x, buv[0].y, buv[1].x, buv[1].y);
    reinterpret_cast<float4*>(&bufUV[par][PAD])[tid * 2 + 1] =
        make_float4(buv[2].x, buv[2].y, buv[3].x, buv[3].y);
    reinterpret_cast<float4*>(&bufSQ[par][PAD])[tid * 2 + 0] =
        make_float4(bsq[0].x, bsq[0].y, bsq[1].x, bsq[1].y);
    reinterpret_cast<float4*>(&bufSQ[par][PAD])[tid * 2 + 1] =
        make_float4(bsq[2].x, bsq[2].y, bsq[3].x, bsq[3].y);
    __syncthreads();

    // horizontal 11-tap blur. Output cols 4t+m need tap cols 4t-5..4t+8:
    // 16-col aligned window [4t+2-PAD .. ] = 8 b128 reads per buffer.
    const int jb = 2 * tid + 1;  // float4 index: cols (4t+2)..(4t+17) absolute
    v2f huv[4], hsq[4];
    {
      v2f t[16];
      const float4* fp4 = reinterpret_cast<const float4*>(&bufUV[par][0]);
#pragma unroll
      for (int e = 0; e < 8; ++e) {
        const float4 r = fp4[jb + e];
        t[2 * e + 0] = (v2f){r.x, r.y};
        t[2 * e + 1] = (v2f){r.z, r.w};
      }
#pragma unroll
      for (int m = 0; m < 4; ++m) {
        v2f s = (v2f){GW[0], GW[0]} * t[m + 1];
#pragma unroll
        for (int k = 1; k < 11; ++k)
          s = __builtin_elementwise_fma((v2f){GW[k], GW[k]}, t[m + 1 + k], s);
        huv[m] = s;
      }
    }
    {
      v2f t[16];
      const float4* fp4 = reinterpret_cast<const float4*>(&bufSQ[par][0]);
#pragma unroll
      for (int e = 0; e < 8; ++e) {
        const float4 r = fp4[jb + e];
        t[2 * e + 0] = (v2f){r.x, r.y};
        t[2 * e + 1] = (v2f){r.z, r.w};
      }
#pragma unroll
      for (int m = 0; m < 4; ++m) {
        v2f s = (v2f){GW[0], GW[0]} * t[m + 1];
#pragma unroll
        for (int k = 1; k < 11; ++k)
          s = __builtin_elementwise_fma((v2f){GW[k], GW[k]}, t[m + 1 + k], s);
        hsq[m] = s;
      }
    }

    // ssim: BU=mu1+mu2, BV=mu1-mu2, BU2=blur((x+y)^2), BV2=blur((x-y)^2)
#pragma unroll
    for (int m = 0; m < 4; ++m) {
      const float BU = huv[m].x, BV = huv[m].y;
      const float BU2 = hsq[m].x, BV2 = hsq[m].y;
      const float P = BU * BU, Q = BV * BV;
      const float PmQ = P - Q, PpQ = P + Q;
      const float An = fmaf(0.5f, PmQ, C1);                // 2*mu1*mu2+C1
      const float Bn = fmaf(0.5f, (BU2 - BV2) - PmQ, C2);  // 2*sigma12+C2
      const float Cd = fmaf(0.5f, PpQ, C1);                // mu1^2+mu2^2+C1
      const float Dd = fmaf(0.5f, (BU2 + BV2) - PpQ, C2);  // s1+s2+C2
      const float num = An * Bn;
      const float den = Cd * Dd;  // >= C1*C2 > 0
      float r = __builtin_amdgcn_rcpf(den);
      r = r * fmaf(-den, r, 2.f);  // one Newton step
      acc = fmaf(num, r, acc);
    }

    // shift the ring (packed 64-bit moves)
#pragma unroll
    for (int k = 0; k < 10; ++k)
#pragma unroll
      for (int c = 0; c < 4; ++c) ruv[k][c] = ruv[k + 1][c];
  }

  // block reduction -> global double accumulator
#pragma unroll
  for (int off = 32; off > 0; off >>= 1) acc += __shfl_down(acc, off, 64);
  if ((tid & 63) == 0) red[tid >> 6] = acc;
  __syncthreads();
  if (tid == 0) {
    float t = 0.f;
#pragma unroll
    for (int wv = 0; wv < BLOCK / 64; ++wv) t += red[wv];
    atomicAdd(ws, (double)t);
  }
}

__global__ void ssim_fin(const double* __restrict__ ws,
                         float* __restrict__ out) {
  out[0] =
      1.0f - (float)(ws[0] * (1.0 / ((double)NIMG * (double)W * (double)H)));
}

extern "C" void kernel_launch(void* const* d_in, const int* in_sizes, int n_in,
                              void* d_out, int out_size, void* d_ws,
                              size_t ws_size, hipStream_t stream) {
  const float* img1 = (const float*)d_in[0];
  const float* img2 = (const float*)d_in[1];
  float* out = (float*)d_out;
  double* ws = (double*)d_ws;

  hipMemsetAsync(d_ws, 0, sizeof(double), stream);
  ssim_main<<<NIMG * NSTRIP, BLOCK, 0, stream>>>(img1, img2, ws);
  ssim_fin<<<1, 1, 0, stream>>>(ws, out);
}

// Round 4
// 326.310 us; speedup vs baseline: 1.0868x; 1.0868x over previous
//
#include <hip/hip_runtime.h>

typedef float v2f __attribute__((ext_vector_type(2)));

namespace {
constexpr int W = 1024;
constexpr int H = 1024;
constexpr int NIMG = 32;
constexpr int SROWS = 32;            // output rows per block strip
constexpr int NSTRIP = H / SROWS;    // 32 -> grid 1024 = 4 blocks/CU
constexpr int BLOCK = 256;           // 256 threads * 4 cols = 1024 cols
// pair-array: 8 zero-pad pair-cols each side of 1024 -> 1040 v2f = 520 float4,
// split into two planes of 260 float4 at float4 granularity.
constexpr int PLANE4 = 260;          // float4 slots per plane

constexpr float C1 = 0.0004f;        // (0.01*2)^2
constexpr float C2 = 0.0036f;        // (0.03*2)^2

// normalized gaussian, sigma=1.5, win=11
constexpr float GW[11] = {
    0.00102838f, 0.00759876f, 0.03600077f, 0.10936070f, 0.21300554f,
    0.26601172f,
    0.21300554f, 0.10936070f, 0.03600077f, 0.00759876f, 0.00102838f};
}  // namespace

// Load one row, produce per-column packed pairs (u,v) = (x+y, x-y).
// y is block-uniform -> uniform branch, no per-lane masking.
__device__ __forceinline__ void load_uv(const float4* __restrict__ p1,
                                        const float4* __restrict__ p2, int y,
                                        int tid, v2f uv[4]) {
  if ((unsigned)y < (unsigned)H) {
    const float4 a = p1[y * (W / 4) + tid];
    const float4 b = p2[y * (W / 4) + tid];
    uv[0] = (v2f){a.x + b.x, a.x - b.x};
    uv[1] = (v2f){a.y + b.y, a.y - b.y};
    uv[2] = (v2f){a.z + b.z, a.z - b.z};
    uv[3] = (v2f){a.w + b.w, a.w - b.w};
  } else {
#pragma unroll
    for (int c = 0; c < 4; ++c) uv[c] = (v2f){0.f, 0.f};
  }
}

// 11-tap horizontal blur over a pre-paired 16-pair window read from the
// two conflict-free planes. t[s] holds pair-col 4t-6+s (buffer-relative).
__device__ __forceinline__ void hblur(const float4* __restrict__ P0,
                                      const float4* __restrict__ P1, int tid,
                                      v2f h[4]) {
  v2f t[16];
#pragma unroll
  for (int e = 0; e < 8; ++e) {
    // original pair-float4 j = 2t+1+e; odd j -> P1[(j-1)/2], even -> P0[j/2]
    const float4 r = (e & 1) ? P0[tid + (e + 1) / 2] : P1[tid + e / 2];
    t[2 * e + 0] = (v2f){r.x, r.y};
    t[2 * e + 1] = (v2f){r.z, r.w};
  }
#pragma unroll
  for (int m = 0; m < 4; ++m) {
    v2f s = (v2f){GW[0], GW[0]} * t[m + 1];
#pragma unroll
    for (int k = 1; k < 11; ++k)
      s = __builtin_elementwise_fma((v2f){GW[k], GW[k]}, t[m + 1 + k], s);
    h[m] = s;
  }
}

// Sum of SSIM map values over the strip; atomicAdd into ws[0] (double).
__global__ __launch_bounds__(BLOCK, 4) void ssim_main(
    const float* __restrict__ img1, const float* __restrict__ img2,
    double* __restrict__ ws) {
  // parity double-buffered, plane-split pair buffers:
  // bufUV = (blur_v(u), blur_v(v)) pairs; bufSQ = (blur_v(u^2), blur_v(v^2))
  __shared__ __align__(16) v2f bufUV[2][2][2 * PLANE4];
  __shared__ __align__(16) v2f bufSQ[2][2][2 * PLANE4];
  __shared__ float red[BLOCK / 64];

  const int tid = threadIdx.x;
  const int bid = blockIdx.x;
  const int img = bid / NSTRIP;
  const int strip = bid % NSTRIP;
  const int ys = strip * SROWS;

  const float4* p1 =
      reinterpret_cast<const float4*>(img1) + (size_t)img * (W / 4) * H;
  const float4* p2 =
      reinterpret_cast<const float4*>(img2) + (size_t)img * (W / 4) * H;

  // zero pad slots: planes P0/P1 slots {0,1,258,259}, both buffers+parities
  if (tid < 32) {
    const int par = tid & 1, b = (tid >> 1) & 1, pl = (tid >> 2) & 1,
              si = tid >> 3;
    const int slot = (si & 1) + ((si >> 1) ? 258 : 0);
    float4* p = reinterpret_cast<float4*>(b ? bufSQ[par][pl] : bufUV[par][pl]);
    p[slot] = make_float4(0.f, 0.f, 0.f, 0.f);
  }

  // shift ring: rows r-5..r+4 in ruv[0..9]; pf prefetches row r+5
  v2f ruv[11][4];
#pragma unroll
  for (int s = 0; s < 10; ++s) load_uv(p1, p2, ys - 5 + s, tid, ruv[s]);
  v2f pf[4];
  load_uv(p1, p2, ys + 5, tid, pf);

  float acc = 0.f;

  for (int ii = 0; ii < SROWS; ++ii) {
    // commit prefetched row r+5, start prefetch of row r+6
#pragma unroll
    for (int c = 0; c < 4; ++c) ruv[10][c] = pf[c];
    load_uv(p1, p2, ys + ii + 6, tid, pf);

    // vertical 11-tap blur: packed (u,v) and (u^2,v^2) accumulators
    v2f buv[4], bsq[4];
#pragma unroll
    for (int c = 0; c < 4; ++c) {
      buv[c] = (v2f){0.f, 0.f};
      bsq[c] = (v2f){0.f, 0.f};
    }
#pragma unroll
    for (int k = 0; k < 11; ++k) {
      const v2f gv = (v2f){GW[k], GW[k]};
#pragma unroll
      for (int c = 0; c < 4; ++c) {
        const v2f x = ruv[k][c];
        const v2f gx = gv * x;                              // pk_mul
        buv[c] += gx;                                       // pk_add
        bsq[c] = __builtin_elementwise_fma(gx, x, bsq[c]);  // pk_fma
      }
    }

    const int par = ii & 1;
    // plane-split stores: pair-float4 F[2t+4] -> P0[t+2], F[2t+5] -> P1[t+2];
    // both contiguous 16B-stride -> conflict-free.
    {
      float4* P0 = reinterpret_cast<float4*>(bufUV[par][0]);
      float4* P1 = reinterpret_cast<float4*>(bufUV[par][1]);
      P0[tid + 2] = make_float4(buv[0].x, buv[0].y, buv[1].x, buv[1].y);
      P1[tid + 2] = make_float4(buv[2].x, buv[2].y, buv[3].x, buv[3].y);
      float4* Q0 = reinterpret_cast<float4*>(bufSQ[par][0]);
      float4* Q1 = reinterpret_cast<float4*>(bufSQ[par][1]);
      Q0[tid + 2] = make_float4(bsq[0].x, bsq[0].y, bsq[1].x, bsq[1].y);
      Q1[tid + 2] = make_float4(bsq[2].x, bsq[2].y, bsq[3].x, bsq[3].y);
    }
    __syncthreads();

    v2f huv[4], hsq[4];
    hblur(reinterpret_cast<const float4*>(bufUV[par][0]),
          reinterpret_cast<const float4*>(bufUV[par][1]), tid, huv);
    hblur(reinterpret_cast<const float4*>(bufSQ[par][0]),
          reinterpret_cast<const float4*>(bufSQ[par][1]), tid, hsq);

    // ssim: BU=mu1+mu2, BV=mu1-mu2, BU2=blur((x+y)^2), BV2=blur((x-y)^2)
#pragma unroll
    for (int m = 0; m < 4; ++m) {
      const float BU = huv[m].x, BV = huv[m].y;
      const float BU2 = hsq[m].x, BV2 = hsq[m].y;
      const float P = BU * BU, Q = BV * BV;
      const float PmQ = P - Q, PpQ = P + Q;
      const float An = fmaf(0.5f, PmQ, C1);                // 2*mu1*mu2+C1
      const float Bn = fmaf(0.5f, (BU2 - BV2) - PmQ, C2);  // 2*sigma12+C2
      const float Cd = fmaf(0.5f, PpQ, C1);                // mu1^2+mu2^2+C1
      const float Dd = fmaf(0.5f, (BU2 + BV2) - PpQ, C2);  // s1+s2+C2
      const float num = An * Bn;
      const float den = Cd * Dd;  // >= C1*C2 > 0
      float r = __builtin_amdgcn_rcpf(den);
      r = r * fmaf(-den, r, 2.f);  // one Newton step
      acc = fmaf(num, r, acc);
    }

    // shift the ring (packed 64-bit moves)
#pragma unroll
    for (int k = 0; k < 10; ++k)
#pragma unroll
      for (int c = 0; c < 4; ++c) ruv[k][c] = ruv[k + 1][c];
  }

  // block reduction -> global double accumulator
#pragma unroll
  for (int off = 32; off > 0; off >>= 1) acc += __shfl_down(acc, off, 64);
  if ((tid & 63) == 0) red[tid >> 6] = acc;
  __syncthreads();
  if (tid == 0) {
    float t = 0.f;
#pragma unroll
    for (int wv = 0; wv < BLOCK / 64; ++wv) t += red[wv];
    atomicAdd(ws, (double)t);
  }
}

__global__ void ssim_fin(const double* __restrict__ ws,
                         float* __restrict__ out) {
  out[0] =
      1.0f - (float)(ws[0] * (1.0 / ((double)NIMG * (double)W * (double)H)));
}

extern "C" void kernel_launch(void* const* d_in, const int* in_sizes, int n_in,
                              void* d_out, int out_size, void* d_ws,
                              size_t ws_size, hipStream_t stream) {
  const float* img1 = (const float*)d_in[0];
  const float* img2 = (const float*)d_in[1];
  float* out = (float*)d_out;
  double* ws = (double*)d_ws;

  hipMemsetAsync(d_ws, 0, sizeof(double), stream);
  ssim_main<<<NIMG * NSTRIP, BLOCK, 0, stream>>>(img1, img2, ws);
  ssim_fin<<<1, 1, 0, stream>>>(ws, out);
}